// Round 9
// baseline (476.240 us; speedup 1.0000x reference)
//
#include <hip/hip_runtime.h>
#include <stdint.h>

#define BB 4096
#define TT 512
#define HH 32
#define SS 4

typedef __attribute__((ext_vector_type(8))) short bf16x8;
typedef __attribute__((ext_vector_type(4))) float f32x4;

union Frag { uint32_t u[4]; bf16x8 v; };

__device__ __forceinline__ uint32_t cvtpk(float a, float b) {
  uint32_t d;
  asm("v_cvt_pk_bf16_f32 %0, %1, %2" : "=v"(d) : "v"(a), "v"(b));
  return d;
}
__device__ __forceinline__ float bflo(uint32_t u) { return __uint_as_float(u << 16); }
__device__ __forceinline__ float bfhi(uint32_t u) { return __uint_as_float(u & 0xFFFF0000u); }

__device__ __forceinline__ float fast_sigm(float a) {
  return __builtin_amdgcn_rcpf(1.0f + __expf(-a));      // v_exp + v_rcp
}
__device__ __forceinline__ float fast_tanh(float y) {
  return 1.0f - 2.0f * __builtin_amdgcn_rcpf(__expf(2.0f * y) + 1.0f);
}
__device__ __forceinline__ float dot4(float4 w, float4 x, float init) {
  return fmaf(w.x, x.x, fmaf(w.y, x.y, fmaf(w.z, x.z, fmaf(w.w, x.w, init))));
}

#define MFMA(acc, afrag, bfrag) \
  acc = __builtin_amdgcn_mfma_f32_16x16x32_bf16((afrag).v, (bfrag).v, acc, 0, 0, 0)

// B-frag build: lane supplies B[k = k0..k0+7][col = c] = w_hh[grow][k0..k0+7]
#define MKB(frag, grow)                                                        \
  { const float4* p_ = (const float4*)(w_hh + (size_t)(grow) * HH + k0);       \
    float4 p0_ = p_[0], p1_ = p_[1];                                           \
    (frag).u[0] = cvtpk(p0_.x, p0_.y); (frag).u[1] = cvtpk(p0_.z, p0_.w);      \
    (frag).u[2] = cvtpk(p1_.x, p1_.y); (frag).u[3] = cvtpk(p1_.z, p1_.w); }

// One wave per 16 batches. Per step: hg[16 x 96] = h[16 x 32] @ w_hh^T via six
// 16x16x32 bf16 MFMA tiles (2-pass hi/lo A for ~f32 accuracy), proj via 2 more
// MFMAs sharing the A-frags. Gates/xg in VALU on the C/D layout
// (col=lane&15, row=4*(lane>>4)+reg — HW-verified mapping). h in LDS f32,
// same-wave write->read ordering (no barriers; 64-thread blocks).
__global__ void __attribute__((amdgpu_flat_work_group_size(64, 64)))
__attribute__((amdgpu_waves_per_eu(1, 4)))
gru_kernel(const float* __restrict__ x, const float* __restrict__ h0,
           const float* __restrict__ w_ih, const float* __restrict__ w_hh,
           const float* __restrict__ b_ih, const float* __restrict__ b_hh,
           const float* __restrict__ w_proj, const float* __restrict__ b_proj,
           float* __restrict__ out) {
  const int lane = threadIdx.x;      // 0..63
  const int c    = lane & 15;        // tile col / A-row
  const int qh   = lane >> 4;        // 0..3
  const int k0   = qh * 8;           // K-slice this lane supplies
  const int b0   = blockIdx.x * 16;  // batch-group base

  __shared__ float  hbuf[16][36];    // h state, f32 (row pad -> 2-way banks max)
  __shared__ float4 xs[2][16];       // x_t double-slot

  // ---- stage h0: lane (c,qh) covers h0[b0+c][k0..k0+7] ----
  {
    const float4* hp = (const float4*)(h0 + (size_t)(b0 + c) * HH + k0);
    float4 a0 = hp[0], a1 = hp[1];
    *(float4*)&hbuf[c][k0]     = a0;
    *(float4*)&hbuf[c][k0 + 4] = a1;
  }
  // ---- stage x_0 ----
  if (lane < 16) {
    xs[0][lane] = *(const float4*)(x + (size_t)(b0 + lane) * TT * 4);
  }

  // ---- loop-invariant per-lane params ----
  const float4* wih4 = (const float4*)w_ih;            // [96][4] rows
  const float4 wr_c = wih4[c],      wr_d = wih4[16 + c];
  const float4 wz_c = wih4[32 + c], wz_d = wih4[48 + c];
  const float4 wn_c = wih4[64 + c], wn_d = wih4[80 + c];

  const float bsr0 = b_ih[c]      + b_hh[c];           // fold into C-init
  const float bsr1 = b_ih[16 + c] + b_hh[16 + c];
  const float bsz0 = b_ih[32 + c] + b_hh[32 + c];
  const float bsz1 = b_ih[48 + c] + b_hh[48 + c];
  const float bin0 = b_ih[64 + c], bin1 = b_ih[80 + c]; // go with xn (outside r*hn)
  const float bhn0 = b_hh[64 + c], bhn1 = b_hh[80 + c]; // C-init of n-tiles
  const float bp   = b_proj[c & 3];

  // ---- B fragments: 6 gate tiles (bf16) + proj (zero-padded cols 4..15) ----
  Frag br0, br1, bz0, bz1, bn0, bn1, bpr;
  MKB(br0, c);       MKB(br1, 16 + c);
  MKB(bz0, 32 + c);  MKB(bz1, 48 + c);
  MKB(bn0, 64 + c);  MKB(bn1, 80 + c);
  if (c < 4) {
    const float4* p = (const float4*)(w_proj + (size_t)c * HH + k0);
    float4 p0 = p[0], p1 = p[1];
    bpr.u[0] = cvtpk(p0.x, p0.y); bpr.u[1] = cvtpk(p0.z, p0.w);
    bpr.u[2] = cvtpk(p1.x, p1.y); bpr.u[3] = cvtpk(p1.z, p1.w);
  } else {
    bpr.u[0] = 0; bpr.u[1] = 0; bpr.u[2] = 0; bpr.u[3] = 0;
  }

  for (int t = 0; t < TT; ++t) {
    // prefetch x_{t+1} (global, waits hidden under this step's work)
    const int tn = (t + 1 < TT) ? (t + 1) : t;
    float4 xpre;
    if (lane < 16) {
      xpre = *(const float4*)(x + (size_t)(b0 + lane) * TT * 4 + (size_t)tn * 4);
    }

    // ---- A-frags (hi/lo bf16 split) from h_{t-1} ----
    const float4 q0 = *(const float4*)&hbuf[c][k0];
    const float4 q1 = *(const float4*)&hbuf[c][k0 + 4];
    Frag ahi, alo;
    ahi.u[0] = cvtpk(q0.x, q0.y); ahi.u[1] = cvtpk(q0.z, q0.w);
    ahi.u[2] = cvtpk(q1.x, q1.y); ahi.u[3] = cvtpk(q1.z, q1.w);
    alo.u[0] = cvtpk(q0.x - bflo(ahi.u[0]), q0.y - bfhi(ahi.u[0]));
    alo.u[1] = cvtpk(q0.z - bflo(ahi.u[1]), q0.w - bfhi(ahi.u[1]));
    alo.u[2] = cvtpk(q1.x - bflo(ahi.u[2]), q1.y - bfhi(ahi.u[2]));
    alo.u[3] = cvtpk(q1.z - bflo(ahi.u[3]), q1.w - bfhi(ahi.u[3]));

    // ---- xg dots + C-init + h_old reads (C/D rows m = 4*qh + i) ----
    f32x4 ar0, ar1, az0, az1, an0, an1, ap;
    float xn0[4], xn1[4], hold0[4], hold1[4];
#pragma unroll
    for (int i = 0; i < 4; ++i) {
      const int m = qh * 4 + i;
      const float4 xv = xs[t & 1][m];
      ar0[i] = dot4(wr_c, xv, bsr0);
      ar1[i] = dot4(wr_d, xv, bsr1);
      az0[i] = dot4(wz_c, xv, bsz0);
      az1[i] = dot4(wz_d, xv, bsz1);
      xn0[i] = dot4(wn_c, xv, bin0);
      xn1[i] = dot4(wn_d, xv, bin1);
      an0[i] = bhn0;
      an1[i] = bhn1;
      ap[i]  = 0.0f;
      hold0[i] = hbuf[m][c];
      hold1[i] = hbuf[m][16 + c];
    }

    // ---- MFMA: 6 gate tiles x 2 passes + proj x 2 ----
    MFMA(ar0, ahi, br0); MFMA(ar0, alo, br0);
    MFMA(ar1, ahi, br1); MFMA(ar1, alo, br1);
    MFMA(az0, ahi, bz0); MFMA(az0, alo, bz0);
    MFMA(az1, ahi, bz1); MFMA(az1, alo, bz1);
    MFMA(an0, ahi, bn0); MFMA(an0, alo, bn0);
    MFMA(an1, ahi, bn1); MFMA(an1, alo, bn1);
    MFMA(ap,  ahi, bpr); MFMA(ap,  alo, bpr);

    // stage x_{t+1} (different slot than the one read above)
    if (lane < 16) xs[(t + 1) & 1][lane] = xpre;

    // ---- deferred projection store: out[t-1] = proj(h_{t-1}) ----
    if (t > 0 && c < 4) {
#pragma unroll
      for (int i = 0; i < 4; ++i) {
        const int m = qh * 4 + i;
        out[(size_t)(b0 + m) * TT * SS + (size_t)(t - 1) * SS + c] = ap[i] + bp;
      }
    }

    // ---- gates + h update (lane owns (m, j=c) and (m, j=16+c)) ----
#pragma unroll
    for (int i = 0; i < 4; ++i) {
      const int m = qh * 4 + i;
      const float r0 = fast_sigm(ar0[i]);
      const float z0 = fast_sigm(az0[i]);
      const float n0 = fast_tanh(fmaf(r0, an0[i], xn0[i]));
      hbuf[m][c] = fmaf(z0, hold0[i] - n0, n0);
      const float r1 = fast_sigm(ar1[i]);
      const float z1 = fast_sigm(az1[i]);
      const float n1 = fast_tanh(fmaf(r1, an1[i], xn1[i]));
      hbuf[m][16 + c] = fmaf(z1, hold1[i] - n1, n1);
    }
  }

  // ---- epilogue: out[TT-1] = proj(h_{TT-1}), and hn = h_{TT-1} ----
  {
    const float4 q0 = *(const float4*)&hbuf[c][k0];
    const float4 q1 = *(const float4*)&hbuf[c][k0 + 4];
    Frag ahi, alo;
    ahi.u[0] = cvtpk(q0.x, q0.y); ahi.u[1] = cvtpk(q0.z, q0.w);
    ahi.u[2] = cvtpk(q1.x, q1.y); ahi.u[3] = cvtpk(q1.z, q1.w);
    alo.u[0] = cvtpk(q0.x - bflo(ahi.u[0]), q0.y - bfhi(ahi.u[0]));
    alo.u[1] = cvtpk(q0.z - bflo(ahi.u[1]), q0.w - bfhi(ahi.u[1]));
    alo.u[2] = cvtpk(q1.x - bflo(ahi.u[2]), q1.y - bfhi(ahi.u[2]));
    alo.u[3] = cvtpk(q1.z - bflo(ahi.u[3]), q1.w - bfhi(ahi.u[3]));
    f32x4 ap = {0.f, 0.f, 0.f, 0.f};
    MFMA(ap, ahi, bpr); MFMA(ap, alo, bpr);
    if (c < 4) {
#pragma unroll
      for (int i = 0; i < 4; ++i) {
        const int m = qh * 4 + i;
        out[(size_t)(b0 + m) * TT * SS + (size_t)(TT - 1) * SS + c] = ap[i] + bp;
      }
    }
    // hn: lane (c,qh) owns h[b0+c][k0..k0+7] = q0,q1
    float* hnp = out + (size_t)BB * TT * SS + (size_t)(b0 + c) * HH + k0;
    *(float4*)hnp       = q0;
    *(float4*)(hnp + 4) = q1;
  }
}

extern "C" void kernel_launch(void* const* d_in, const int* in_sizes, int n_in,
                              void* d_out, int out_size, void* d_ws, size_t ws_size,
                              hipStream_t stream) {
  const float* x      = (const float*)d_in[0];
  const float* h0     = (const float*)d_in[1];
  const float* w_ih   = (const float*)d_in[2];
  const float* w_hh   = (const float*)d_in[3];
  const float* b_ih   = (const float*)d_in[4];
  const float* b_hh   = (const float*)d_in[5];
  const float* w_proj = (const float*)d_in[6];
  const float* b_proj = (const float*)d_in[7];
  float* out = (float*)d_out;

  dim3 grid(BB / 16), block(64);
  hipLaunchKernelGGL(gru_kernel, grid, block, 0, stream,
                     x, h0, w_ih, w_hh, b_ih, b_hh, w_proj, b_proj, out);
}

// Round 11
// 420.075 us; speedup vs baseline: 1.1337x; 1.1337x over previous
//
#include <hip/hip_runtime.h>
#include <stdint.h>

#define BB 4096
#define TT 512
#define HH 32
#define SS 4

typedef float v2f __attribute__((ext_vector_type(2)));

__device__ __forceinline__ float fast_sigm(float a) {
  return __builtin_amdgcn_rcpf(1.0f + __expf(-a));      // v_exp + v_rcp
}
__device__ __forceinline__ float fast_tanh(float y) {
  return 1.0f - 2.0f * __builtin_amdgcn_rcpf(__expf(2.0f * y) + 1.0f);
}
// packed 2xf32 FMA (VOP3P, proven in r7): c = a*b + c elementwise
__device__ __forceinline__ v2f pkfma(v2f a, v2f b, v2f c) {
  asm("v_pk_fma_f32 %0, %1, %2, %0" : "+v"(c) : "v"(a), "v"(b));
  return c;
}

// r5 parallel shape (2 batches/wave, 2048 waves, 2/SIMD) with ZERO persistent
// weight registers and ZERO scratch: w_hh lives in LDS as f32 (shared by the
// block's 8 batches), read per-step as per-lane ds_read_b128. Row stride 36
// floats -> each 32-lane group's quad reads hit every bank exactly 4x (the
// 128-word hardware minimum, no counted conflicts); the two groups read the
// same addresses (same j) -> broadcast dedup. GEMV = 48 v_pk_fma_f32.
// h state per batch in LDS f32 (same-wave write->read, proven r4-r8).
__global__ void __launch_bounds__(256, 2)
gru_kernel(const float* __restrict__ x, const float* __restrict__ h0,
           const float* __restrict__ w_ih, const float* __restrict__ w_hh,
           const float* __restrict__ b_ih, const float* __restrict__ b_hh,
           const float* __restrict__ w_proj, const float* __restrict__ b_proj,
           float* __restrict__ out) {
  const int tid  = threadIdx.x;
  const int wid  = tid >> 6;        // wave 0..3
  const int lane = tid & 63;
  const int g    = lane >> 5;       // batch within wave
  const int j    = lane & 31;       // h index owned by this lane
  const int row  = wid * 2 + g;     // LDS h row 0..7
  const int b    = blockIdx.x * 8 + row;
  const int s_idx = j & 3;          // proj channel
  const int c_idx = j >> 2;         // proj h-chunk

  __shared__ float wl[96][36];      // w_hh rows, stride 36 floats (144B)
  __shared__ float hl[8][36];       // h state per batch row

  // ---- cooperative weight staging: 768 float4 copies, 3 per thread ----
  for (int idx = tid; idx < 96 * 8; idx += 256) {
    const int r = idx >> 3, q = idx & 7;
    *(float4*)&wl[r][q * 4] = *(const float4*)(w_hh + r * HH + q * 4);
  }
  __syncthreads();

  // ---- per-lane invariants (small) ----
  const float4* wih4 = (const float4*)w_ih;
  const float4 wir = wih4[j], wiz = wih4[32 + j], win = wih4[64 + j];
  const float bir = b_ih[j], biz = b_ih[32 + j], bin_ = b_ih[64 + j];
  const float bhr = b_hh[j], bhz = b_hh[32 + j], bhn = b_hh[64 + j];
  const float4 wp = ((const float4*)w_proj)[s_idx * 8 + c_idx];
  const float bp = b_proj[s_idx];

  float* lrow = &hl[row][0];
  const float* wrp = &wl[j][0];
  const float* wzp = &wl[32 + j][0];
  const float* wnp = &wl[64 + j][0];
  const float* hc_addr = lrow + (c_idx << 2);

  float h_self = h0[(size_t)b * HH + j];
  lrow[j] = h_self;

  const float4* xp = (const float4*)(x + (size_t)b * TT * 4);
  float* outp = out + (size_t)b * TT * SS;

  float4 xv = xp[0];

  for (int t = 0; t <= TT; ++t) {
    // per-lane proj chunk of h_{t-1} (read before this step's h write)
    const float4 hcv = *(const float4*)hc_addr;

    // deferred projection: out[t-1] = proj(h after step t-1)
    if (t > 0) {
      float v = fmaf(wp.x, hcv.x, fmaf(wp.y, hcv.y,
                fmaf(wp.z, hcv.z, wp.w * hcv.w)));
      v += __shfl_xor(v, 4, 64);
      v += __shfl_xor(v, 8, 64);
      v += __shfl_xor(v, 16, 64);
      if (c_idx == 0) outp[(t - 1) * SS + s_idx] = v + bp;
    }
    if (t == TT) break;

    float4 xvn = xp[(t + 1 < TT) ? (t + 1) : t];   // next-step x prefetch

    // input-gate contributions (f32)
    float xr = fmaf(wir.x, xv.x, fmaf(wir.y, xv.y, fmaf(wir.z, xv.z, fmaf(wir.w, xv.w, bir))));
    float xz = fmaf(wiz.x, xv.x, fmaf(wiz.y, xv.y, fmaf(wiz.z, xv.z, fmaf(wiz.w, xv.w, biz))));
    float xn = fmaf(win.x, xv.x, fmaf(win.y, xv.y, fmaf(win.z, xv.z, fmaf(win.w, xv.w, bin_))));

    // hidden GEMV: 48 pk_fma; weights + h streamed from LDS each step
    v2f aR = (v2f){bhr, 0.f}, aZ = (v2f){bhz, 0.f}, aN = (v2f){bhn, 0.f};
#pragma unroll
    for (int kq = 0; kq < 8; ++kq) {
      const float4 hv = *(const float4*)(lrow + kq * 4);   // broadcast read
      const float4 qr = *(const float4*)(wrp + kq * 4);    // per-lane row reads
      const float4 qz = *(const float4*)(wzp + kq * 4);
      const float4 qn = *(const float4*)(wnp + kq * 4);
      const v2f h01 = (v2f){hv.x, hv.y}, h23 = (v2f){hv.z, hv.w};
      aR = pkfma((v2f){qr.x, qr.y}, h01, aR); aR = pkfma((v2f){qr.z, qr.w}, h23, aR);
      aZ = pkfma((v2f){qz.x, qz.y}, h01, aZ); aZ = pkfma((v2f){qz.z, qz.w}, h23, aZ);
      aN = pkfma((v2f){qn.x, qn.y}, h01, aN); aN = pkfma((v2f){qn.z, qn.w}, h23, aN);
    }
    const float hr = aR.x + aR.y;
    const float hz = aZ.x + aZ.y;
    const float hn = aN.x + aN.y;

    const float r  = fast_sigm(xr + hr);
    const float zz = fast_sigm(xz + hz);
    const float nn = fast_tanh(fmaf(r, hn, xn));
    const float hnew = fmaf(zz, h_self - nn, nn);  // (1-z)n + z h
    h_self = hnew;

    lrow[j] = hnew;   // publish h_t (same-wave, in-order DS pipe)

    xv = xvn;
  }

  // hn output: [1, B, H] appended after state (f32)
  out[(size_t)BB * TT * SS + (size_t)b * HH + j] = h_self;
}

extern "C" void kernel_launch(void* const* d_in, const int* in_sizes, int n_in,
                              void* d_out, int out_size, void* d_ws, size_t ws_size,
                              hipStream_t stream) {
  const float* x      = (const float*)d_in[0];
  const float* h0     = (const float*)d_in[1];
  const float* w_ih   = (const float*)d_in[2];
  const float* w_hh   = (const float*)d_in[3];
  const float* b_ih   = (const float*)d_in[4];
  const float* b_hh   = (const float*)d_in[5];
  const float* w_proj = (const float*)d_in[6];
  const float* b_proj = (const float*)d_in[7];
  float* out = (float*)d_out;

  dim3 grid(BB / 8), block(256);
  hipLaunchKernelGGL(gru_kernel, grid, block, 0, stream,
                     x, h0, w_ih, w_hh, b_ih, b_hh, w_proj, b_proj, out);
}

// Round 12
// 291.804 us; speedup vs baseline: 1.6321x; 1.4396x over previous
//
#include <hip/hip_runtime.h>
#include <stdint.h>

#define BB 4096
#define TT 512
#define HH 32
#define SS 4

typedef float v2f __attribute__((ext_vector_type(2)));

#define STR2(x) #x
#define STR(x) STR2(x)
// Non-sinkable, non-rematerializable loads: compiler must keep results live.
#define GLOAD4(dst, ptr, off)                                                  \
  asm volatile("global_load_dwordx4 %0, %1, off offset:" STR(off)              \
               : "=v"(dst) : "v"(ptr))
#define GLOAD1(dst, ptr, off)                                                  \
  asm volatile("global_load_dword %0, %1, off offset:" STR(off)                \
               : "=v"(dst) : "v"(ptr))

__device__ __forceinline__ float fast_sigm(float a) {
  return __builtin_amdgcn_rcpf(1.0f + __expf(-a));      // v_exp + v_rcp
}
__device__ __forceinline__ float fast_tanh(float y) {
  return 1.0f - 2.0f * __builtin_amdgcn_rcpf(__expf(2.0f * y) + 1.0f);
}
// packed 2xf32 FMA (VOP3P): c = a*b + c elementwise
__device__ __forceinline__ v2f pkfma(v2f a, v2f b, v2f c) {
  asm("v_pk_fma_f32 %0, %1, %2, %0" : "+v"(c) : "v"(a), "v"(b));
  return c;
}

// r7 structure (asm-volatile weight loads -> unsinkable) PLUS waves_per_eu(2,2)
// (RA budget 512/2 = 256 VGPR -> no reason to spill). r7 alone spilled to
// scratch because launch_bounds' waves-per-eu is a FLOOR and RA climbed to ~5
// waves/EU (96 VGPR); r8 alone had plain loads that the pre-RA scheduler sank
// before RA saw pressure. Each failure mode needs its own counter; this is the
// first kernel with both.
__global__ void __attribute__((amdgpu_flat_work_group_size(256, 256)))
__attribute__((amdgpu_waves_per_eu(2, 2))) gru_kernel(
    const float* __restrict__ x, const float* __restrict__ h0,
    const float* __restrict__ w_ih, const float* __restrict__ w_hh,
    const float* __restrict__ b_ih, const float* __restrict__ b_hh,
    const float* __restrict__ w_proj, const float* __restrict__ b_proj,
    float* __restrict__ out) {
  const int tid  = threadIdx.x;
  const int wid  = tid >> 6;        // wave in block 0..3
  const int lane = tid & 63;
  const int g    = lane >> 5;       // which batch of the wave's two
  const int j    = lane & 31;       // h index owned by this lane
  const int row  = wid * 2 + g;     // LDS row 0..7
  const int b    = blockIdx.x * 8 + row;

  __shared__ float lds_h[8][36];    // 144B row stride (conflict-free, r5)
  float* lrow = &lds_h[row][0];

  const int s_idx = j & 3;          // proj channel this lane reduces
  const int c_idx = j >> 2;         // h-chunk (of 8) this lane covers

  // ---- asm-volatile preload of ALL loop-invariant parameters ----
  float4 wq[24];                    // w_hh rows j, j+32, j+64 (96 floats)
  float4 wih_r, wih_z, wih_n;       // w_ih rows (I=4 -> one float4 each)
  float4 wp;                        // w_proj row chunk
  float bir, biz, bin_, bhr, bhz, bhn, bp;
  {
    const char* p0 = (const char*)(w_hh + (0 * HH + j) * HH);
    const char* p1 = (const char*)(w_hh + (1 * HH + j) * HH);
    const char* p2 = (const char*)(w_hh + (2 * HH + j) * HH);
    GLOAD4(wq[0],  p0, 0);  GLOAD4(wq[1],  p0, 16);
    GLOAD4(wq[2],  p0, 32); GLOAD4(wq[3],  p0, 48);
    GLOAD4(wq[4],  p0, 64); GLOAD4(wq[5],  p0, 80);
    GLOAD4(wq[6],  p0, 96); GLOAD4(wq[7],  p0, 112);
    GLOAD4(wq[8],  p1, 0);  GLOAD4(wq[9],  p1, 16);
    GLOAD4(wq[10], p1, 32); GLOAD4(wq[11], p1, 48);
    GLOAD4(wq[12], p1, 64); GLOAD4(wq[13], p1, 80);
    GLOAD4(wq[14], p1, 96); GLOAD4(wq[15], p1, 112);
    GLOAD4(wq[16], p2, 0);  GLOAD4(wq[17], p2, 16);
    GLOAD4(wq[18], p2, 32); GLOAD4(wq[19], p2, 48);
    GLOAD4(wq[20], p2, 64); GLOAD4(wq[21], p2, 80);
    GLOAD4(wq[22], p2, 96); GLOAD4(wq[23], p2, 112);
    const char* pi = (const char*)(w_ih + j * 4);   // gate stride 32 rows*16B=512B
    GLOAD4(wih_r, pi, 0); GLOAD4(wih_z, pi, 512); GLOAD4(wih_n, pi, 1024);
    const char* pbi = (const char*)(b_ih + j);      // gate stride 128B
    GLOAD1(bir, pbi, 0); GLOAD1(biz, pbi, 128); GLOAD1(bin_, pbi, 256);
    const char* pbh = (const char*)(b_hh + j);
    GLOAD1(bhr, pbh, 0); GLOAD1(bhz, pbh, 128); GLOAD1(bhn, pbh, 256);
    const char* pp = (const char*)(w_proj + (s_idx * 8 + c_idx) * 4);
    GLOAD4(wp, pp, 0);
    const char* pbp = (const char*)(b_proj + s_idx);
    GLOAD1(bp, pbp, 0);
    asm volatile("s_waitcnt vmcnt(0)" ::: "memory");
    __builtin_amdgcn_sched_barrier(0);
  }

  // View the 96 w_hh floats as 48 v2f pairs (register aliasing, no moves)
  v2f wr2[16], wz2[16], wn2[16];
#pragma unroll
  for (int c = 0; c < 8; ++c) {
    wr2[2*c] = (v2f){wq[c].x,    wq[c].y};    wr2[2*c+1] = (v2f){wq[c].z,    wq[c].w};
    wz2[2*c] = (v2f){wq[8+c].x,  wq[8+c].y};  wz2[2*c+1] = (v2f){wq[8+c].z,  wq[8+c].w};
    wn2[2*c] = (v2f){wq[16+c].x, wq[16+c].y}; wn2[2*c+1] = (v2f){wq[16+c].z, wq[16+c].w};
  }

  float h_self = h0[(size_t)b * HH + j];
  lrow[j] = h_self;

  const float4* xp = (const float4*)(x + (size_t)b * TT * 4);  // 512 float4
  float* outp = out + (size_t)b * TT * SS;
  const float* hc_addr = lrow + (c_idx << 2);

  float4 xv = xp[0];

  for (int t = 0; t <= TT; ++t) {
    // broadcast-read h_{t-1}: 8x b128 (2 distinct addrs/wave) + proj chunk
    v2f h2[16];
#pragma unroll
    for (int c = 0; c < 8; ++c) {
      const float4 q = *(const float4*)(lrow + 4 * c);
      h2[2*c] = (v2f){q.x, q.y}; h2[2*c+1] = (v2f){q.z, q.w};
    }
    const float4 hcv = *(const float4*)hc_addr;

    // deferred projection: out[t-1] = proj(h_{t-1})
    if (t > 0) {
      float v = fmaf(wp.x, hcv.x, fmaf(wp.y, hcv.y,
                fmaf(wp.z, hcv.z, wp.w * hcv.w)));
      v += __shfl_xor(v, 4, 64);
      v += __shfl_xor(v, 8, 64);
      v += __shfl_xor(v, 16, 64);
      if (c_idx == 0) {
        outp[(t - 1) * SS + s_idx] = v + bp;
      }
    }
    if (t == TT) break;

    float4 xvn = xp[(t + 1 < TT) ? (t + 1) : t];   // next-step x prefetch

    // input-gate contributions (I=4)
    float xr = fmaf(wih_r.x, xv.x, fmaf(wih_r.y, xv.y, fmaf(wih_r.z, xv.z, fmaf(wih_r.w, xv.w, bir))));
    float xz = fmaf(wih_z.x, xv.x, fmaf(wih_z.y, xv.y, fmaf(wih_z.z, xv.z, fmaf(wih_z.w, xv.w, biz))));
    float xn = fmaf(wih_n.x, xv.x, fmaf(wih_n.y, xv.y, fmaf(wih_n.z, xv.z, fmaf(wih_n.w, xv.w, bin_))));

    // hidden-gate contributions: 48 packed FMAs, bias folded into init
    v2f aR = (v2f){bhr, 0.f}, aZ = (v2f){bhz, 0.f}, aN = (v2f){bhn, 0.f};
#pragma unroll
    for (int m = 0; m < 16; ++m) {
      aR = pkfma(wr2[m], h2[m], aR);
      aZ = pkfma(wz2[m], h2[m], aZ);
      aN = pkfma(wn2[m], h2[m], aN);
    }
    const float hr = aR.x + aR.y;
    const float hz = aZ.x + aZ.y;
    const float hn = aN.x + aN.y;

    const float r  = fast_sigm(xr + hr);
    const float zz = fast_sigm(xz + hz);
    const float nn = fast_tanh(fmaf(r, hn, xn));
    const float hnew = fmaf(zz, h_self - nn, nn);  // (1-z)n + z h
    h_self = hnew;

    lrow[j] = hnew;   // publish h_t (same-wave, in-order DS pipe)

    xv = xvn;
  }

  // hn output: [1, B, H] appended after state (float32)
  out[(size_t)BB * TT * SS + (size_t)b * HH + j] = h_self;
}

extern "C" void kernel_launch(void* const* d_in, const int* in_sizes, int n_in,
                              void* d_out, int out_size, void* d_ws, size_t ws_size,
                              hipStream_t stream) {
  const float* x      = (const float*)d_in[0];
  const float* h0     = (const float*)d_in[1];
  const float* w_ih   = (const float*)d_in[2];
  const float* w_hh   = (const float*)d_in[3];
  const float* b_ih   = (const float*)d_in[4];
  const float* b_hh   = (const float*)d_in[5];
  const float* w_proj = (const float*)d_in[6];
  const float* b_proj = (const float*)d_in[7];
  float* out = (float*)d_out;

  dim3 grid(BB / 8), block(256);
  hipLaunchKernelGGL(gru_kernel, grid, block, 0, stream,
                     x, h0, w_ih, w_hh, b_ih, b_hh, w_proj, b_proj, out);
}